// Round 14
// baseline (4714.141 us; speedup 1.0000x reference)
//
#include <hip/hip_runtime.h>

#define Bn   128
#define Tn   512
#define Kn   12
#define Hn   256
#define NWG  256
#define ARR      32768            // 128*256 elements per state array
#define SSTRIDE  (4*ARR)          // ushorts per state buffer (h_hi,h_lo,c_hi,c_lo)
#define CTRL_BYTES 6144           // slots[256]@0, xcd_cnt[32]@1024, flag[(x*4+g)]@2048+idx*128
#define HWREG_XCC_ID 63508        // hwreg(HW_REG_XCC_ID=20, offset 0, size 32)

typedef __attribute__((ext_vector_type(8))) short bf16x8;
typedef __attribute__((ext_vector_type(4))) float f32x4;

__device__ inline unsigned short f2bf(float x) {
  union { float f; unsigned u; } v; v.f = x;
  unsigned r = v.u + 0x7fffu + ((v.u >> 16) & 1u);
  return (unsigned short)(r >> 16);
}
__device__ inline float bf2f(unsigned short h) {
  union { unsigned u; float f; } v; v.u = ((unsigned)h) << 16;
  return v.f;
}
// Fast activations: v_exp_f32-based, ~4x cheaper than ocml tanhf (which sits
// on the serial chain 3x/step). Clamp keeps e finite -> no NaN. Per-call abs
// error ~1e-7; through the exact-fp32 c recurrence over 512 steps the output
// perturbation is ~1e-5..1e-4, 30x under the 3.5e-3 threshold.
__device__ inline float sigmf(float x) {
  return __fdividef(1.0f, 1.0f + __expf(-x));
}
__device__ inline float ftanh(float x) {
  float xc = fminf(fmaxf(x, -15.0f), 15.0f);
  float e = __expf(-2.0f * xc);
  return __fdividef(1.0f - e, 1.0f + e);
}

// ROUND-13 PROVEN KERNEL (absmax 0.0, 4.21ms): per-(XCD,group) leaders,
// slot/flag barrier, sc1 write-through state, per-XCD acquire inv. Protocol
// byte-identical here. Changes are arithmetic-only:
//  (a) tanhf -> ftanh (hw v_exp), IEEE div -> __fdividef (3 critical-path
//      sites: wave0 epilogue 8/thread, waves1-3 8/thread, owner 4/thread);
//  (b) wave0's x@W_ih dot hoisted BEFORE the GEMM (independent of MFMA
//      results — moves ~100 VALU ops off the post-GEMM serial path).
__global__ void __launch_bounds__(256, 1) mtlstm_kernel(
    const float* __restrict__ xd, const float* __restrict__ dtp,
    const float* __restrict__ wih, const float* __restrict__ whh,
    const float* __restrict__ bias, const float* __restrict__ wdc,
    const float* __restrict__ bdc, unsigned char* __restrict__ ws)
{
  __shared__ __align__(16) float xs_lds[32 * Kn];
  __shared__ __align__(16) float dt_lds[32 * Kn];
  __shared__ float g_lds[32 * 16];      // activated gates [b_local][jj*4+g]
  __shared__ float dsum_lds[32 * 48];   // decomp contribs [b_local][jj][k]
  __shared__ unsigned ld_info[2];       // [0]=is_leader, [1]=flag index

  unsigned* slots    = (unsigned*)ws;                 // [256], monotone gens
  unsigned* xcd_cnt  = (unsigned*)(ws + 1024);        // [32] rank counters (xcd*4+bg)
  unsigned* flags    = (unsigned*)(ws + 2048);        // flag[idx] at +idx*32 u32 (128B apart)
  unsigned short* state = (unsigned short*)(ws + CTRL_BYTES);
  float* h_final = (float*)(ws + CTRL_BYTES + 2 * SSTRIDE * 2);

  const int tid = threadIdx.x;
  const int wv  = tid >> 6;        // wave 0: gates(h); waves 1..3: decomp(c)
  const int l   = tid & 63;
  const int n   = l & 15;          // MFMA col / A-row within tile
  const int oct = l >> 4;          // k-octet

  const int wgid = blockIdx.x;
  const int bg = wgid >> 6;        // batch group 0..3 (32 b each)
  const int j0 = (wgid & 63) * 4;  // 4 j-columns per WG

  // ---- one-time: leader election, one per (XCD, group) pair ----
  if (tid == 0) {
    unsigned xcd = __builtin_amdgcn_s_getreg(HWREG_XCC_ID) & 7u;
    unsigned idx = xcd * 4u + (unsigned)bg;
    unsigned r = __hip_atomic_fetch_add(xcd_cnt + idx, 1u, __ATOMIC_RELAXED,
                                        __HIP_MEMORY_SCOPE_AGENT);
    ld_info[0] = (r == 0u);
    ld_info[1] = idx;
  }

  // ---- one-time weight setup: per-lane 16 cols x 256 k, split hi/lo bf16 ----
  const float* rowp;
  float biasv;
  int kd = 0, jjd = 0;
  float wx[12];
  if (wv == 0) {
    int jj = n >> 2, g = n & 3;
    int grow = g * Hn + j0 + jj;
    rowp = whh + (size_t)grow * Hn;
    biasv = bias[grow];
#pragma unroll
    for (int kk = 0; kk < 12; ++kk) wx[kk] = wih[grow * 12 + kk];
  } else {
    int q = (wv - 1) * 16 + n;     // 0..47
    int jj = q / 12;
    int k  = q - jj * 12;
    kd = k; jjd = jj;
    rowp = wdc + ((size_t)k * Hn + (j0 + jj)) * Hn;
    biasv = bdc[k * Hn + j0 + jj];
#pragma unroll
    for (int kk = 0; kk < 12; ++kk) wx[kk] = 0.f;
  }

  bf16x8 wh[8], wl[8];
#pragma unroll
  for (int ks = 0; ks < 8; ++ks) {
    const float* p = rowp + ks * 32 + oct * 8;
#pragma unroll
    for (int e = 0; e < 8; ++e) {
      float x = p[e];
      unsigned short hi = f2bf(x);
      unsigned short lo = f2bf(x - bf2f(hi));
      wh[ks][e] = (short)hi;
      wl[ks][e] = (short)lo;
    }
  }

  const int aoff0 = (bg * 32 + n) * Hn + oct * 8;  // M-tile 0 A offset
  const int aoff1 = aoff0 + 16 * Hn;               // M-tile 1
  const int hsel  = (wv == 0) ? 0 : 2 * ARR;       // h arrays vs c arrays

  float c_reg[4] = {0.f, 0.f, 0.f, 0.f};  // exact fp32 c, owners tid<32 (4 j each)
  unsigned gen = 0;

  // ---- prologue: stage x_0, dt_0 ----
  if (tid < 96) {
    int bl = tid / 3, ch = tid % 3;
    float4 v = *(const float4*)(xd + ((size_t)(bg * 32 + bl) * Tn + 0) * Kn + ch * 4);
    *(float4*)(&xs_lds[bl * 12 + ch * 4]) = v;
  } else if (tid < 192) {
    int q2 = tid - 96;
    int bl = q2 / 3, ch = q2 % 3;
    float4 v = *(const float4*)(dtp + ((size_t)(bg * 32 + bl) * Tn + 0) * Kn + ch * 4);
    *(float4*)(&dt_lds[bl * 12 + ch * 4]) = v;
  }
  __syncthreads();
  const bool leader = ld_info[0] != 0u;
  unsigned* myflag = flags + ld_info[1] * 32;
  unsigned* gslot = slots + bg * 64;     // this group's 64 slots (2 lines)

  for (int t = 0; t < Tn; ++t) {
    const unsigned short* sb = state + (t & 1) * SSTRIDE + hsel;

    // ---- wave0: x @ W_ih hoisted ahead of the GEMM (independent of state) ----
    float xw[2][4];
    if (wv == 0) {
#pragma unroll
      for (int mt = 0; mt < 2; ++mt)
#pragma unroll
        for (int r = 0; r < 4; ++r) {
          int bl = mt * 16 + oct * 4 + r;
          float s = 0.f;
#pragma unroll
          for (int kk = 0; kk < 12; ++kk) s += xs_lds[bl * 12 + kk] * wx[kk];
          xw[mt][r] = s;
        }
    }

    // ---- GEMM: 2 M-tiles x 1 N-tile, K=256, split-bf16 (3 MFMA) ----
    f32x4 acc0 = {0.f, 0.f, 0.f, 0.f};
    f32x4 acc1 = {0.f, 0.f, 0.f, 0.f};
#pragma unroll
    for (int ks = 0; ks < 8; ++ks) {
      int o = ks * 32;
      bf16x8 a0h = *(const bf16x8*)(sb + aoff0 + o);
      bf16x8 a1h = *(const bf16x8*)(sb + aoff1 + o);
      bf16x8 a0l = *(const bf16x8*)(sb + ARR + aoff0 + o);
      bf16x8 a1l = *(const bf16x8*)(sb + ARR + aoff1 + o);
      acc0 = __builtin_amdgcn_mfma_f32_16x16x32_bf16(a0h, wh[ks], acc0, 0, 0, 0);
      acc1 = __builtin_amdgcn_mfma_f32_16x16x32_bf16(a1h, wh[ks], acc1, 0, 0, 0);
      acc0 = __builtin_amdgcn_mfma_f32_16x16x32_bf16(a0h, wl[ks], acc0, 0, 0, 0);
      acc1 = __builtin_amdgcn_mfma_f32_16x16x32_bf16(a1h, wl[ks], acc1, 0, 0, 0);
      acc0 = __builtin_amdgcn_mfma_f32_16x16x32_bf16(a0l, wh[ks], acc0, 0, 0, 0);
      acc1 = __builtin_amdgcn_mfma_f32_16x16x32_bf16(a1l, wh[ks], acc1, 0, 0, 0);
    }

    // ---- epilogue: D layout row=(oct*4+r) (=b_local within tile), col=n ----
    if (wv == 0) {
      int g = n & 3;
#pragma unroll
      for (int mt = 0; mt < 2; ++mt) {
        f32x4 a = mt ? acc1 : acc0;
#pragma unroll
        for (int r = 0; r < 4; ++r) {
          int bl = mt * 16 + oct * 4 + r;
          float v = a[r] + biasv + xw[mt][r];
          float act = (g == 2) ? ftanh(v) : sigmf(v);
          g_lds[bl * 16 + n] = act;
        }
      }
    } else {
#pragma unroll
      for (int mt = 0; mt < 2; ++mt) {
        f32x4 a = mt ? acc1 : acc0;
#pragma unroll
        for (int r = 0; r < 4; ++r) {
          int bl = mt * 16 + oct * 4 + r;
          float cs = ftanh(a[r] + biasv);
          float dtv = dt_lds[bl * 12 + kd];
          float coef = __fdividef(1.0f, __logf(2.718281828459045f + dtv)) - 1.0f;
          dsum_lds[bl * 48 + jjd * 12 + kd] = cs * coef;
        }
      }
    }
    __syncthreads();   // C: g_lds/dsum_lds ready for owner; xs(t) reads done

    ++gen;
    if (wv == 0) {
      // ---- owner update (tid<32) + packed 8B sc1 stores ----
      if (tid < 32) {
        int b = tid;
        union P { unsigned short u[4]; unsigned long long q; } ph, pl, pc, pq;
#pragma unroll
        for (int jj = 0; jj < 4; ++jj) {
          float iv = g_lds[b * 16 + jj * 4 + 0];
          float fv = g_lds[b * 16 + jj * 4 + 1];
          float gv = g_lds[b * 16 + jj * 4 + 2];
          float ov = g_lds[b * 16 + jj * 4 + 3];
          float S = 0.f;
#pragma unroll
          for (int k = 0; k < 12; ++k) S += dsum_lds[b * 48 + jj * 12 + k];
          float cst = c_reg[jj] + S;
          float cn = fv * cst + iv * gv;
          float hn = ov * ftanh(cn);
          c_reg[jj] = cn;
          ph.u[jj] = f2bf(hn);
          pl.u[jj] = f2bf(hn - bf2f(ph.u[jj]));
          pc.u[jj] = f2bf(cn);
          pq.u[jj] = f2bf(cn - bf2f(pc.u[jj]));
          if (t == Tn - 1)
            h_final[(size_t)(bg * 32 + b) * Hn + j0 + jj] = hn;
        }
        unsigned long long* db = (unsigned long long*)state
            + (size_t)((t + 1) & 1) * (SSTRIDE / 4)
            + (size_t)(bg * 32 + b) * 64 + (j0 >> 2);
        __hip_atomic_store(db + 0 * (ARR / 4), ph.q, __ATOMIC_RELAXED, __HIP_MEMORY_SCOPE_AGENT);
        __hip_atomic_store(db + 1 * (ARR / 4), pl.q, __ATOMIC_RELAXED, __HIP_MEMORY_SCOPE_AGENT);
        __hip_atomic_store(db + 2 * (ARR / 4), pc.q, __ATOMIC_RELAXED, __HIP_MEMORY_SCOPE_AGENT);
        __hip_atomic_store(db + 3 * (ARR / 4), pq.q, __ATOMIC_RELAXED, __HIP_MEMORY_SCOPE_AGENT);
      }
      // wave-0-only drain: owner stores ack'd at MALL before slot store
      asm volatile("s_waitcnt vmcnt(0)" ::: "memory");
      if (tid == 0)
        __hip_atomic_store(slots + wgid, gen, __ATOMIC_RELAXED,
                           __HIP_MEMORY_SCOPE_AGENT);
      if (leader) {
        // poll THIS GROUP's 64 slots (1 load/lane) — r10 position & semantics
        for (;;) {
          unsigned v = __hip_atomic_load(gslot + l, __ATOMIC_RELAXED,
                                         __HIP_MEMORY_SCOPE_AGENT);
          if (__all((int)(v >= gen))) break;
          __builtin_amdgcn_s_sleep(1);
        }
        __builtin_amdgcn_fence(__ATOMIC_ACQUIRE, "agent");  // inv my XCD's L2
        if (tid == 0)
          __hip_atomic_store(myflag, gen, __ATOMIC_RELAXED, __HIP_MEMORY_SCOPE_AGENT);
      } else {
        // single-lane flag poll: flag==gen => group state at MALL + my L2 inv'd
        for (;;) {
          unsigned v = gen;
          if (l == 0)
            v = __hip_atomic_load(myflag, __ATOMIC_RELAXED, __HIP_MEMORY_SCOPE_AGENT);
          if (__all((int)(v >= gen))) break;
          __builtin_amdgcn_s_sleep(1);
        }
      }
    } else if (t + 1 < Tn) {
      // ---- waves 1-3: stage x_{t+1}, dt_{t+1} during the barrier window ----
      int q = tid - 64;            // 0..191
      if (q < 96) {
        int bl = q / 3, ch = q % 3;
        float4 v = *(const float4*)(xd + ((size_t)(bg * 32 + bl) * Tn + (t + 1)) * Kn + ch * 4);
        *(float4*)(&xs_lds[bl * 12 + ch * 4]) = v;
      } else {
        int q2 = q - 96;
        int bl = q2 / 3, ch = q2 % 3;
        float4 v = *(const float4*)(dtp + ((size_t)(bg * 32 + bl) * Tn + (t + 1)) * Kn + ch * 4);
        *(float4*)(&dt_lds[bl * 12 + ch * 4]) = v;
      }
    }
    __syncthreads();   // D: barrier passed + x/dt(t+1) staged
  }
}

__global__ void out_gemv(const float* __restrict__ hf, const float* __restrict__ lw,
                         const float* __restrict__ lb, float* __restrict__ out)
{
  int b = blockIdx.x;
  int l = threadIdx.x;
  const float* row = hf + b * Hn;
  float s = row[l] * lw[l] + row[l + 64] * lw[l + 64]
          + row[l + 128] * lw[l + 128] + row[l + 192] * lw[l + 192];
#pragma unroll
  for (int off = 32; off > 0; off >>= 1) s += __shfl_down(s, off, 64);
  if (l == 0) out[b] = s + lb[0];
}

extern "C" void kernel_launch(void* const* d_in, const int* in_sizes, int n_in,
                              void* d_out, int out_size, void* d_ws, size_t ws_size,
                              hipStream_t stream)
{
  const float* xd   = (const float*)d_in[0];
  const float* dtp  = (const float*)d_in[1];
  const float* wih  = (const float*)d_in[2];
  const float* whh  = (const float*)d_in[3];
  const float* bias = (const float*)d_in[4];
  const float* wdc  = (const float*)d_in[5];
  const float* bdc  = (const float*)d_in[6];
  const float* lw   = (const float*)d_in[7];
  const float* lb   = (const float*)d_in[8];
  float* out = (float*)d_out;
  unsigned char* ws = (unsigned char*)d_ws;

  // zero slots + counters/flags + both state buffers (ws poisoned 0xAA)
  hipMemsetAsync(ws, 0, CTRL_BYTES + 2 * SSTRIDE * 2, stream);

  void* args[] = { (void*)&xd, (void*)&dtp, (void*)&wih, (void*)&whh,
                   (void*)&bias, (void*)&wdc, (void*)&bdc, (void*)&ws };
  hipLaunchCooperativeKernel((const void*)mtlstm_kernel, dim3(NWG), dim3(256),
                             args, 0, stream);

  const float* hf = (const float*)(ws + CTRL_BYTES + 2 * SSTRIDE * 2);
  out_gemv<<<dim3(Bn), dim3(64), 0, stream>>>(hf, lw, lb, out);
}

// Round 15
// 4190.520 us; speedup vs baseline: 1.1250x; 1.1250x over previous
//
#include <hip/hip_runtime.h>

#define Bn   128
#define Tn   512
#define Kn   12
#define Hn   256
#define NWG  256
#define ARR      32768            // 128*256 elements per state array
#define SSTRIDE  (4*ARR)          // ushorts per state buffer (h_hi,h_lo,c_hi,c_lo)
#define CTRL_BYTES 6144           // slots[256]@0, xcd_cnt[32]@1024, flag[(x*4+g)]@2048+idx*128
#define HWREG_XCC_ID 63508        // hwreg(HW_REG_XCC_ID=20, offset 0, size 32)

typedef __attribute__((ext_vector_type(8))) short bf16x8;
typedef __attribute__((ext_vector_type(4))) float f32x4;

__device__ inline unsigned short f2bf(float x) {
  union { float f; unsigned u; } v; v.f = x;
  unsigned r = v.u + 0x7fffu + ((v.u >> 16) & 1u);
  return (unsigned short)(r >> 16);
}
__device__ inline float bf2f(unsigned short h) {
  union { unsigned u; float f; } v; v.u = ((unsigned)h) << 16;
  return v.f;
}
__device__ inline float sigmf(float x) { return 1.0f / (1.0f + __expf(-x)); }

// ROUND-13 KERNEL, VERBATIM — the session's proven best (absmax 0.0, 4.21ms).
// r14's two "optimizations" both regressed and are reverted:
//  - x@W_ih hoist: in the epilogue those ~100 VALU ops were FREE (hidden
//    under the MFMA-result s_waitcnt); hoisted before the GEMM they delayed
//    wave0's A-load issue — wave0 is the serial-chain wave (owner+barrier).
//  - ftanh/__fdividef: no cheaper than ocml tanhf (already v_exp-based);
//    VALU busy-cycles rose 17%.
// Architecture: 256 WGs (1/CU, cooperative), WG=(bg: 32 batches)x(4 j-cols).
// wave0: 16 gate cols (A=h); waves1-3: 48 decomp cols (A=c). Split-bf16
// (hi+lo, 3 MFMA) keeps recurrence numerics exact to output rounding; owner
// threads keep exact fp32 c in registers across all 512 steps. State is
// double-buffered in d_ws; owners publish via packed 8B agent-scope (sc1)
// write-through atomic stores. Per-step sync (the product of rounds 4-13,
// 33.6 -> 8.2 us/step): wave0-only vmcnt drain -> per-WG slot store ->
// per-(XCD,group) leader polls its group's 64 slots -> ONE acquire fence
// (L2 inv) per XCD per group -> 128B-isolated flag -> consumers single-lane
// poll. The 4 batch-group recurrences are fully independent and never
// cross-couple. Remaining 8.2 us/step is the irreducible MALL
// store->ack->signal->inv->read chain + 64-WG straggler skew (MfmaUtil 4%,
// VALUBusy 9% — a latency floor, not a memory/compute roofline).
__global__ void __launch_bounds__(256, 1) mtlstm_kernel(
    const float* __restrict__ xd, const float* __restrict__ dtp,
    const float* __restrict__ wih, const float* __restrict__ whh,
    const float* __restrict__ bias, const float* __restrict__ wdc,
    const float* __restrict__ bdc, unsigned char* __restrict__ ws)
{
  __shared__ __align__(16) float xs_lds[32 * Kn];
  __shared__ __align__(16) float dt_lds[32 * Kn];
  __shared__ float g_lds[32 * 16];      // activated gates [b_local][jj*4+g]
  __shared__ float dsum_lds[32 * 48];   // decomp contribs [b_local][jj][k]
  __shared__ unsigned ld_info[2];       // [0]=is_leader, [1]=flag index

  unsigned* slots    = (unsigned*)ws;                 // [256], monotone gens
  unsigned* xcd_cnt  = (unsigned*)(ws + 1024);        // [32] rank counters (xcd*4+bg)
  unsigned* flags    = (unsigned*)(ws + 2048);        // flag[idx] at +idx*32 u32 (128B apart)
  unsigned short* state = (unsigned short*)(ws + CTRL_BYTES);
  float* h_final = (float*)(ws + CTRL_BYTES + 2 * SSTRIDE * 2);

  const int tid = threadIdx.x;
  const int wv  = tid >> 6;        // wave 0: gates(h); waves 1..3: decomp(c)
  const int l   = tid & 63;
  const int n   = l & 15;          // MFMA col / A-row within tile
  const int oct = l >> 4;          // k-octet

  const int wgid = blockIdx.x;
  const int bg = wgid >> 6;        // batch group 0..3 (32 b each)
  const int j0 = (wgid & 63) * 4;  // 4 j-columns per WG

  // ---- one-time: leader election, one per (XCD, group) pair ----
  if (tid == 0) {
    unsigned xcd = __builtin_amdgcn_s_getreg(HWREG_XCC_ID) & 7u;
    unsigned idx = xcd * 4u + (unsigned)bg;
    unsigned r = __hip_atomic_fetch_add(xcd_cnt + idx, 1u, __ATOMIC_RELAXED,
                                        __HIP_MEMORY_SCOPE_AGENT);
    ld_info[0] = (r == 0u);
    ld_info[1] = idx;
  }

  // ---- one-time weight setup: per-lane 16 cols x 256 k, split hi/lo bf16 ----
  const float* rowp;
  float biasv;
  int kd = 0, jjd = 0;
  float wx[12];
  if (wv == 0) {
    int jj = n >> 2, g = n & 3;
    int grow = g * Hn + j0 + jj;
    rowp = whh + (size_t)grow * Hn;
    biasv = bias[grow];
#pragma unroll
    for (int kk = 0; kk < 12; ++kk) wx[kk] = wih[grow * 12 + kk];
  } else {
    int q = (wv - 1) * 16 + n;     // 0..47
    int jj = q / 12;
    int k  = q - jj * 12;
    kd = k; jjd = jj;
    rowp = wdc + ((size_t)k * Hn + (j0 + jj)) * Hn;
    biasv = bdc[k * Hn + j0 + jj];
#pragma unroll
    for (int kk = 0; kk < 12; ++kk) wx[kk] = 0.f;
  }

  bf16x8 wh[8], wl[8];
#pragma unroll
  for (int ks = 0; ks < 8; ++ks) {
    const float* p = rowp + ks * 32 + oct * 8;
#pragma unroll
    for (int e = 0; e < 8; ++e) {
      float x = p[e];
      unsigned short hi = f2bf(x);
      unsigned short lo = f2bf(x - bf2f(hi));
      wh[ks][e] = (short)hi;
      wl[ks][e] = (short)lo;
    }
  }

  const int aoff0 = (bg * 32 + n) * Hn + oct * 8;  // M-tile 0 A offset
  const int aoff1 = aoff0 + 16 * Hn;               // M-tile 1
  const int hsel  = (wv == 0) ? 0 : 2 * ARR;       // h arrays vs c arrays

  float c_reg[4] = {0.f, 0.f, 0.f, 0.f};  // exact fp32 c, owners tid<32 (4 j each)
  unsigned gen = 0;

  // ---- prologue: stage x_0, dt_0 ----
  if (tid < 96) {
    int bl = tid / 3, ch = tid % 3;
    float4 v = *(const float4*)(xd + ((size_t)(bg * 32 + bl) * Tn + 0) * Kn + ch * 4);
    *(float4*)(&xs_lds[bl * 12 + ch * 4]) = v;
  } else if (tid < 192) {
    int q2 = tid - 96;
    int bl = q2 / 3, ch = q2 % 3;
    float4 v = *(const float4*)(dtp + ((size_t)(bg * 32 + bl) * Tn + 0) * Kn + ch * 4);
    *(float4*)(&dt_lds[bl * 12 + ch * 4]) = v;
  }
  __syncthreads();
  const bool leader = ld_info[0] != 0u;
  unsigned* myflag = flags + ld_info[1] * 32;
  unsigned* gslot = slots + bg * 64;     // this group's 64 slots (2 lines)

  for (int t = 0; t < Tn; ++t) {
    const unsigned short* sb = state + (t & 1) * SSTRIDE + hsel;

    // ---- GEMM: 2 M-tiles x 1 N-tile, K=256, split-bf16 (3 MFMA) ----
    f32x4 acc0 = {0.f, 0.f, 0.f, 0.f};
    f32x4 acc1 = {0.f, 0.f, 0.f, 0.f};
#pragma unroll
    for (int ks = 0; ks < 8; ++ks) {
      int o = ks * 32;
      bf16x8 a0h = *(const bf16x8*)(sb + aoff0 + o);
      bf16x8 a1h = *(const bf16x8*)(sb + aoff1 + o);
      bf16x8 a0l = *(const bf16x8*)(sb + ARR + aoff0 + o);
      bf16x8 a1l = *(const bf16x8*)(sb + ARR + aoff1 + o);
      acc0 = __builtin_amdgcn_mfma_f32_16x16x32_bf16(a0h, wh[ks], acc0, 0, 0, 0);
      acc1 = __builtin_amdgcn_mfma_f32_16x16x32_bf16(a1h, wh[ks], acc1, 0, 0, 0);
      acc0 = __builtin_amdgcn_mfma_f32_16x16x32_bf16(a0h, wl[ks], acc0, 0, 0, 0);
      acc1 = __builtin_amdgcn_mfma_f32_16x16x32_bf16(a1h, wl[ks], acc1, 0, 0, 0);
      acc0 = __builtin_amdgcn_mfma_f32_16x16x32_bf16(a0l, wh[ks], acc0, 0, 0, 0);
      acc1 = __builtin_amdgcn_mfma_f32_16x16x32_bf16(a1l, wh[ks], acc1, 0, 0, 0);
    }

    // ---- epilogue: D layout row=(oct*4+r) (=b_local within tile), col=n ----
    // (x@W_ih stays HERE: it executes under the MFMA-result waitcnt shadow)
    if (wv == 0) {
      int g = n & 3;
#pragma unroll
      for (int mt = 0; mt < 2; ++mt) {
        f32x4 a = mt ? acc1 : acc0;
#pragma unroll
        for (int r = 0; r < 4; ++r) {
          int bl = mt * 16 + oct * 4 + r;
          float xwv = 0.f;
#pragma unroll
          for (int kk = 0; kk < 12; ++kk) xwv += xs_lds[bl * 12 + kk] * wx[kk];
          float v = a[r] + biasv + xwv;
          float act = (g == 2) ? tanhf(v) : sigmf(v);
          g_lds[bl * 16 + n] = act;
        }
      }
    } else {
#pragma unroll
      for (int mt = 0; mt < 2; ++mt) {
        f32x4 a = mt ? acc1 : acc0;
#pragma unroll
        for (int r = 0; r < 4; ++r) {
          int bl = mt * 16 + oct * 4 + r;
          float v = a[r] + biasv;
          float cs = tanhf(v);
          float dtv = dt_lds[bl * 12 + kd];
          float coef = 1.0f / __logf(2.718281828459045f + dtv) - 1.0f;
          dsum_lds[bl * 48 + jjd * 12 + kd] = cs * coef;
        }
      }
    }
    __syncthreads();   // C: g_lds/dsum_lds ready for owner; xs(t) reads done

    ++gen;
    if (wv == 0) {
      // ---- owner update (tid<32) + packed 8B sc1 stores ----
      if (tid < 32) {
        int b = tid;
        union P { unsigned short u[4]; unsigned long long q; } ph, pl, pc, pq;
#pragma unroll
        for (int jj = 0; jj < 4; ++jj) {
          float iv = g_lds[b * 16 + jj * 4 + 0];
          float fv = g_lds[b * 16 + jj * 4 + 1];
          float gv = g_lds[b * 16 + jj * 4 + 2];
          float ov = g_lds[b * 16 + jj * 4 + 3];
          float S = 0.f;
#pragma unroll
          for (int k = 0; k < 12; ++k) S += dsum_lds[b * 48 + jj * 12 + k];
          float cst = c_reg[jj] + S;
          float cn = fv * cst + iv * gv;
          float hn = ov * tanhf(cn);
          c_reg[jj] = cn;
          ph.u[jj] = f2bf(hn);
          pl.u[jj] = f2bf(hn - bf2f(ph.u[jj]));
          pc.u[jj] = f2bf(cn);
          pq.u[jj] = f2bf(cn - bf2f(pc.u[jj]));
          if (t == Tn - 1)
            h_final[(size_t)(bg * 32 + b) * Hn + j0 + jj] = hn;
        }
        unsigned long long* db = (unsigned long long*)state
            + (size_t)((t + 1) & 1) * (SSTRIDE / 4)
            + (size_t)(bg * 32 + b) * 64 + (j0 >> 2);
        __hip_atomic_store(db + 0 * (ARR / 4), ph.q, __ATOMIC_RELAXED, __HIP_MEMORY_SCOPE_AGENT);
        __hip_atomic_store(db + 1 * (ARR / 4), pl.q, __ATOMIC_RELAXED, __HIP_MEMORY_SCOPE_AGENT);
        __hip_atomic_store(db + 2 * (ARR / 4), pc.q, __ATOMIC_RELAXED, __HIP_MEMORY_SCOPE_AGENT);
        __hip_atomic_store(db + 3 * (ARR / 4), pq.q, __ATOMIC_RELAXED, __HIP_MEMORY_SCOPE_AGENT);
      }
      // wave-0-only drain: owner stores ack'd at MALL before slot store
      asm volatile("s_waitcnt vmcnt(0)" ::: "memory");
      if (tid == 0)
        __hip_atomic_store(slots + wgid, gen, __ATOMIC_RELAXED,
                           __HIP_MEMORY_SCOPE_AGENT);
      if (leader) {
        // poll THIS GROUP's 64 slots (1 load/lane) — r10 position & semantics
        for (;;) {
          unsigned v = __hip_atomic_load(gslot + l, __ATOMIC_RELAXED,
                                         __HIP_MEMORY_SCOPE_AGENT);
          if (__all((int)(v >= gen))) break;
          __builtin_amdgcn_s_sleep(1);
        }
        __builtin_amdgcn_fence(__ATOMIC_ACQUIRE, "agent");  // inv my XCD's L2
        if (tid == 0)
          __hip_atomic_store(myflag, gen, __ATOMIC_RELAXED, __HIP_MEMORY_SCOPE_AGENT);
      } else {
        // single-lane flag poll: flag==gen => group state at MALL + my L2 inv'd
        for (;;) {
          unsigned v = gen;
          if (l == 0)
            v = __hip_atomic_load(myflag, __ATOMIC_RELAXED, __HIP_MEMORY_SCOPE_AGENT);
          if (__all((int)(v >= gen))) break;
          __builtin_amdgcn_s_sleep(1);
        }
      }
    } else if (t + 1 < Tn) {
      // ---- waves 1-3: stage x_{t+1}, dt_{t+1} during the barrier window ----
      int q = tid - 64;            // 0..191
      if (q < 96) {
        int bl = q / 3, ch = q % 3;
        float4 v = *(const float4*)(xd + ((size_t)(bg * 32 + bl) * Tn + (t + 1)) * Kn + ch * 4);
        *(float4*)(&xs_lds[bl * 12 + ch * 4]) = v;
      } else {
        int q2 = q - 96;
        int bl = q2 / 3, ch = q2 % 3;
        float4 v = *(const float4*)(dtp + ((size_t)(bg * 32 + bl) * Tn + (t + 1)) * Kn + ch * 4);
        *(float4*)(&dt_lds[bl * 12 + ch * 4]) = v;
      }
    }
    __syncthreads();   // D: barrier passed + x/dt(t+1) staged
  }
}

__global__ void out_gemv(const float* __restrict__ hf, const float* __restrict__ lw,
                         const float* __restrict__ lb, float* __restrict__ out)
{
  int b = blockIdx.x;
  int l = threadIdx.x;
  const float* row = hf + b * Hn;
  float s = row[l] * lw[l] + row[l + 64] * lw[l + 64]
          + row[l + 128] * lw[l + 128] + row[l + 192] * lw[l + 192];
#pragma unroll
  for (int off = 32; off > 0; off >>= 1) s += __shfl_down(s, off, 64);
  if (l == 0) out[b] = s + lb[0];
}

extern "C" void kernel_launch(void* const* d_in, const int* in_sizes, int n_in,
                              void* d_out, int out_size, void* d_ws, size_t ws_size,
                              hipStream_t stream)
{
  const float* xd   = (const float*)d_in[0];
  const float* dtp  = (const float*)d_in[1];
  const float* wih  = (const float*)d_in[2];
  const float* whh  = (const float*)d_in[3];
  const float* bias = (const float*)d_in[4];
  const float* wdc  = (const float*)d_in[5];
  const float* bdc  = (const float*)d_in[6];
  const float* lw   = (const float*)d_in[7];
  const float* lb   = (const float*)d_in[8];
  float* out = (float*)d_out;
  unsigned char* ws = (unsigned char*)d_ws;

  // zero slots + counters/flags + both state buffers (ws poisoned 0xAA)
  hipMemsetAsync(ws, 0, CTRL_BYTES + 2 * SSTRIDE * 2, stream);

  void* args[] = { (void*)&xd, (void*)&dtp, (void*)&wih, (void*)&whh,
                   (void*)&bias, (void*)&wdc, (void*)&bdc, (void*)&ws };
  hipLaunchCooperativeKernel((const void*)mtlstm_kernel, dim3(NWG), dim3(256),
                             args, 0, stream);

  const float* hf = (const float*)(ws + CTRL_BYTES + 2 * SSTRIDE * 2);
  out_gemv<<<dim3(Bn), dim3(64), 0, stream>>>(hf, lw, lb, out);
}